// Round 17
// baseline (111.679 us; speedup 1.0000x reference)
//
#include <hip/hip_runtime.h>
#include <hip/hip_bf16.h>

#define NROWS 131072
#define KIN   784
#define H1N   128
#define H2N   64
#define OUTN  10

// packed W1: w1p[kb][kg][col_s] dword; kb=0..24, kg=0..3, col_s=(col+8*kg)&127,
// nibble j = int4 of w1q[col][kb*32+kg*8+j] (zero for k>=784).
#define W1P_DW    12800
#define W2C_ELEMS (16 * 64 * 8)    // bf16, k-chunked
#define W3_ELEMS  (16 * 64)        // bf16

typedef short s16x8 __attribute__((ext_vector_type(8)));
typedef float f32x4 __attribute__((ext_vector_type(4)));
typedef __hip_bfloat16 bf16;

static __device__ __forceinline__ short b2s(float f) {
    bf16 h = __float2bfloat16(f);
    return *reinterpret_cast<short*>(&h);
}
static __device__ __forceinline__ s16x8 cvt8(f32x4 a, f32x4 b) {
    s16x8 r;
    r[0] = b2s(a[0]); r[1] = b2s(a[1]); r[2] = b2s(a[2]); r[3] = b2s(a[3]);
    r[4] = b2s(b[0]); r[5] = b2s(b[1]); r[6] = b2s(b[2]); r[7] = b2s(b[3]);
    return r;
}
// 8 int4 nibbles -> bf16x8 (values -8..7 exact in bf16)
static __device__ __forceinline__ s16x8 unpack8(unsigned d) {
    s16x8 r;
#pragma unroll
    for (int j = 0; j < 8; ++j) {
        int v = ((int)(d << (28 - 4 * j))) >> 28;
        r[j] = b2s((float)v);
    }
    return r;
}
static __device__ __forceinline__ void gl2lds16(const void* g, char* l) {
    __builtin_amdgcn_global_load_lds(
        (const __attribute__((address_space(1))) void*)g,
        (__attribute__((address_space(3))) void*)l, 16, 0, 0);
}
static __device__ __forceinline__ void gl2lds4(const void* g, char* l) {
    __builtin_amdgcn_global_load_lds(
        (const __attribute__((address_space(1))) void*)g,
        (__attribute__((address_space(3))) void*)l, 4, 0, 0);
}

#define WAITV(N) do { asm volatile("s_waitcnt vmcnt(" #N ")" ::: "memory"); \
                      __builtin_amdgcn_sched_barrier(0); } while (0)
#define WAITL()  do { asm volatile("s_waitcnt lgkmcnt(0)" ::: "memory"); \
                      __builtin_amdgcn_sched_barrier(0); } while (0)
#define BAR()    __builtin_amdgcn_s_barrier()

// ---------------- prep: pack W1 int4; dequant W2/W3 to bf16 ------------------
__global__ __launch_bounds__(256) void dequant_kernel(
    const int* __restrict__ w1q, const float* __restrict__ s1,
    const int* __restrict__ w2q, const float* __restrict__ s2,
    const int* __restrict__ w3q, const float* __restrict__ s3,
    unsigned* __restrict__ w1p, bf16* __restrict__ w2c, bf16* __restrict__ w3d)
{
    const int total = W1P_DW + W2C_ELEMS + W3_ELEMS;
    for (int i = blockIdx.x * blockDim.x + threadIdx.x; i < total;
         i += gridDim.x * blockDim.x) {
        if (i < W1P_DW) {
            int kb = i >> 9, rem = i & 511;
            int kg = rem >> 7, col_s = rem & 127;
            int col = (col_s - 8 * kg) & 127;
            unsigned d = 0;
#pragma unroll
            for (int j = 0; j < 8; ++j) {
                int k = kb * 32 + kg * 8 + j;
                unsigned q = 0;
                if (k < KIN) q = (unsigned)w1q[col * KIN + k] & 0xFu;
                d |= q << (4 * j);
            }
            w1p[i] = d;
        } else if (i < W1P_DW + W2C_ELEMS) {
            int t = i - W1P_DW;
            int kb = t >> 9, rem = t & 511;
            int col = rem >> 3, j = rem & 7;
            int k = kb * 8 + j;
            w2c[t] = __float2bfloat16((float)w2q[col * H1N + k] * s2[col]);
        } else {
            int t = i - W1P_DW - W2C_ELEMS;
            int r = t >> 6, c = t & 63;
            float v = 0.0f;
            if (r < OUTN) v = (float)w3q[r * H2N + c] * s3[r];
            w3d[t] = __float2bfloat16(v);
        }
    }
}

// ---------------- fused MLP ------------------------------------------------
// r14 champion structure UNCHANGED (256 thr / 64-row tile / 2x2 wave
// decomposition / int4-B staging / 2-slot ring / WAITV(4) depth-2 / 2 raw
// barriers / grid 2048 / LDS 25.6KB). Single change: __launch_bounds__(256,6)
// -> 6 blocks/CU = 24 waves/CU (LDS allows 6x25.6=153.6KB).
__global__ __launch_bounds__(256, 6) void mlp_kernel(
    const float* __restrict__ x,
    const unsigned* __restrict__ w1p,
    const bf16*  __restrict__ w2c,
    const bf16*  __restrict__ w3d,
    const float* __restrict__ s1,
    const float* __restrict__ b1,
    const float* __restrict__ b2,
    const float* __restrict__ b3,
    float* __restrict__ out)
{
    __shared__ __align__(16) char lds[25600];
    // A slots: [0,8K),[8K,16K): 64 rows x 128B (row r at r*128, seg-swizzled)
    // B slots: [16K,18K),[18K,20K): packed int4 window, 512 dwords [kg][col_s]
    // post-loop: h1 [64][132] shorts at 0 (16896B); h2 [64][68] at 16896.

    const int tid  = threadIdx.x;
    const int lane = tid & 63;
    const int wv   = tid >> 6;
    const int r16  = lane & 15;
    const int kg   = lane >> 4;     // 0..3
    const int kgo  = kg * 8;
    const int rg   = wv >> 1;       // row group 0..1 (32 rows)
    const int cg   = wv & 1;        // col group 0..1 (64 cols)

    const int i3 = lane >> 3;       // staging row-in-group 0..7
    const int i7 = lane & 7;        // staging 16B-slot 0..7
    const int sw = i7 ^ i3;         // swizzled global seg
    const int adj = (sw >= 4) ? 16 : 0;

    const long long rowBlk = (long long)blockIdx.x * 64;
    const float* gA0 = x + (rowBlk + wv * 16 + i3) * (long long)KIN + sw * 4;
    const float* gA1 = gA0 + 8LL * KIN;
    const unsigned* gBp = w1p + wv * 128 + lane;

    const int aoff = (rg * 32 + r16) * 128 + (((2 * kg) ^ (r16 & 7)) * 16);
    const int bcol = cg * 64 + r16 + 8 * kg;

    // stage window w into slot s (uniform 4 vmem ops per wave)
#define STAGE(W, S) do {                                                      \
        char* ad_ = lds + (S) * 8192 + wv * 2048;                             \
        char* bd_ = lds + 16384 + (S) * 2048 + wv * 512;                      \
        if ((W) < 24) {                                                       \
            gl2lds16(gA0 + (W) * 32, ad_);                                    \
            gl2lds16(gA1 + (W) * 32, ad_ + 1024);                             \
            gl2lds4(gBp + (W) * 512, bd_);                                    \
            gl2lds4(gBp + (W) * 512 + 64, bd_ + 256);                         \
        } else {            /* tail: A segs>=4 redirected in-row */           \
            gl2lds16(gA0 + 768 - adj, ad_);                                   \
            gl2lds16(gA1 + 768 - adj, ad_ + 1024);                            \
            gl2lds4(gBp + 24 * 512, bd_);                                     \
            gl2lds4(gBp + 24 * 512 + 64, bd_ + 256);                          \
        }                                                                     \
    } while (0)

    // prologue: windows 0,1 -> slots 0,1 (8 ops airborne)
    STAGE(0, 0);
    STAGE(1, 1);

    f32x4 acc1[2][4];
#pragma unroll
    for (int i = 0; i < 2; ++i)
#pragma unroll
        for (int j = 0; j < 4; ++j) acc1[i][j] = (f32x4){0.f, 0.f, 0.f, 0.f};

#pragma unroll 1
    for (int t = 0; t < 24; ++t) {
        WAITV(4);                 // window t's 4 ops retired (t+1 airborne)
        BAR();                    // all waves' shares landed
        const char* sa = lds + (t & 1) * 8192;
        f32x4 q00 = *(const f32x4*)(sa + aoff);
        f32x4 q01 = *(const f32x4*)(sa + (aoff ^ 16));
        f32x4 q10 = *(const f32x4*)(sa + aoff + 2048);
        f32x4 q11 = *(const f32x4*)(sa + (aoff ^ 16) + 2048);
        const char* sb = lds + 16384 + (t & 1) * 2048 + kg * 512;
        unsigned bw4[4];
#pragma unroll
        for (int nj = 0; nj < 4; ++nj)
            bw4[nj] = *(const unsigned*)(sb + (((bcol + nj * 16) & 127) << 2));
        WAITL();                  // reads in registers
        BAR();                    // all waves done with slot t&1
        if (t < 23) STAGE(t + 2, (t & 1));   // refill the just-freed slot
        s16x8 a0 = cvt8(q00, q01);
        s16x8 a1 = cvt8(q10, q11);
#pragma unroll
        for (int nj = 0; nj < 4; ++nj) {
            s16x8 bf = unpack8(bw4[nj]);
            acc1[0][nj] = __builtin_amdgcn_mfma_f32_16x16x32_bf16(a0, bf, acc1[0][nj], 0, 0, 0);
            acc1[1][nj] = __builtin_amdgcn_mfma_f32_16x16x32_bf16(a1, bf, acc1[1][nj], 0, 0, 0);
        }
    }
    {   // peeled window 24 (k 768..799; packed weights zero for k>=784)
        WAITV(0);
        BAR();
        const char* sa = lds + (24 & 1) * 8192;
        f32x4 q00 = *(const f32x4*)(sa + aoff);
        f32x4 q01 = *(const f32x4*)(sa + (aoff ^ 16));
        f32x4 q10 = *(const f32x4*)(sa + aoff + 2048);
        f32x4 q11 = *(const f32x4*)(sa + (aoff ^ 16) + 2048);
        const char* sb = lds + 16384 + (24 & 1) * 2048 + kg * 512;
        unsigned bw4[4];
#pragma unroll
        for (int nj = 0; nj < 4; ++nj)
            bw4[nj] = *(const unsigned*)(sb + (((bcol + nj * 16) & 127) << 2));
        WAITL();
        BAR();                    // ring fully dead -> arenas may overlay
        s16x8 a0 = cvt8(q00, q01);
        s16x8 a1 = cvt8(q10, q11);
#pragma unroll
        for (int nj = 0; nj < 4; ++nj) {
            s16x8 bf = unpack8(bw4[nj]);
            acc1[0][nj] = __builtin_amdgcn_mfma_f32_16x16x32_bf16(a0, bf, acc1[0][nj], 0, 0, 0);
            acc1[1][nj] = __builtin_amdgcn_mfma_f32_16x16x32_bf16(a1, bf, acc1[1][nj], 0, 0, 0);
        }
    }
#undef STAGE

    // ---- h1 (block-level [64][132] shorts at lds+0): scale+bias+relu -------
    short* h1s = (short*)lds;
#pragma unroll
    for (int nj = 0; nj < 4; ++nj) {
        const int col = cg * 64 + nj * 16 + r16;
        const float sc1 = s1[col];
        const float bb = b1[col];
#pragma unroll
        for (int mi = 0; mi < 2; ++mi)
#pragma unroll
            for (int r = 0; r < 4; ++r) {
                const int row = rg * 32 + mi * 16 + kg * 4 + r;
                h1s[row * 132 + col] = b2s(fmaxf(acc1[mi][nj][r] * sc1 + bb, 0.0f));
            }
    }
    __syncthreads();   // h1 rows cross wave boundaries

    // ---- layer 2: [16 x 128] @ [128 x 64] per wave (rows wv*16..) ----------
    f32x4 acc2[4];
#pragma unroll
    for (int j = 0; j < 4; ++j) acc2[j] = (f32x4){0.f, 0.f, 0.f, 0.f};

#pragma unroll
    for (int it = 0; it < 4; ++it) {
        const int kk = it * 32 + kgo;
        s16x8 a = *(const s16x8*)(h1s + (wv * 16 + r16) * 132 + kk);
        const bf16* bp2 = w2c + (size_t)(it * 4 + kg) * 512 + (size_t)r16 * 8;
#pragma unroll
        for (int nj = 0; nj < 4; ++nj) {
            s16x8 b = *(const s16x8*)(bp2 + nj * 128);
            acc2[nj] = __builtin_amdgcn_mfma_f32_16x16x32_bf16(a, b, acc2[nj], 0, 0, 0);
        }
    }

    // h2 at lds+16896: [64][68] shorts; wave writes/reads its own 16 rows
    short* h2s = (short*)(lds + 16896);
#pragma unroll
    for (int nj = 0; nj < 4; ++nj) {
        const int col = nj * 16 + r16;
        const float bb = b2[col];
#pragma unroll
        for (int r = 0; r < 4; ++r)
            h2s[(wv * 16 + kg * 4 + r) * 68 + col] = b2s(fmaxf(acc2[nj][r] + bb, 0.0f));
    }

    // ---- layer 3: [16 x 64] @ [64 x 16] (rows 10..15 of W3 zero) -----------
    f32x4 acc3 = (f32x4){0.f, 0.f, 0.f, 0.f};
#pragma unroll
    for (int it = 0; it < 2; ++it) {
        const int kk = it * 32 + kgo;
        s16x8 a = *(const s16x8*)(h2s + (wv * 16 + r16) * 68 + kk);
        s16x8 b = *(const s16x8*)(w3d + r16 * H2N + kk);
        acc3 = __builtin_amdgcn_mfma_f32_16x16x32_bf16(a, b, acc3, 0, 0, 0);
    }

    // out stage in wave's own (dead) h1 rows
    float* ob = (float*)(lds + (wv * 16) * 264);
    const float bb3 = (r16 < OUTN) ? b3[r16] : 0.0f;
#pragma unroll
    for (int r = 0; r < 4; ++r) {
        const int row = kg * 4 + r;
        if (r16 < OUTN) ob[row * OUTN + r16] = acc3[r] + bb3;
    }
    const long long obase = (rowBlk + wv * 16) * OUTN;
    for (int i = lane; i < 16 * OUTN; i += 64) out[obase + i] = ob[i];
}

extern "C" void kernel_launch(void* const* d_in, const int* in_sizes, int n_in,
                              void* d_out, int out_size, void* d_ws, size_t ws_size,
                              hipStream_t stream) {
    const float* x   = (const float*)d_in[0];
    const int*   w1q = (const int*)d_in[1];
    const float* s1  = (const float*)d_in[2];
    const float* b1  = (const float*)d_in[3];
    const int*   w2q = (const int*)d_in[4];
    const float* s2  = (const float*)d_in[5];
    const float* b2  = (const float*)d_in[6];
    const int*   w3q = (const int*)d_in[7];
    const float* s3  = (const float*)d_in[8];
    const float* b3  = (const float*)d_in[9];
    float* out = (float*)d_out;

    unsigned* w1p = (unsigned*)d_ws;           // 12800 dwords
    bf16* w2c = (bf16*)(w1p + W1P_DW);         // [16][64][8]
    bf16* w3d = w2c + W2C_ELEMS;               // [16][64]

    dequant_kernel<<<128, 256, 0, stream>>>(w1q, s1, w2q, s2, w3q, s3, w1p, w2c, w3d);
    mlp_kernel<<<NROWS / 64, 256, 0, stream>>>(x, w1p, w2c, w3d, s1, b1, b2, b3, out);
}

// Round 18
// 94.754 us; speedup vs baseline: 1.1786x; 1.1786x over previous
//
#include <hip/hip_runtime.h>
#include <hip/hip_bf16.h>

#define NROWS 131072
#define KIN   784
#define H1N   128
#define H2N   64
#define OUTN  10

// packed W1: w1p[kb][kg][col_s] dword; kb=0..24, kg=0..3, col_s=(col+8*kg)&127,
// nibble j = int4 of w1q[col][kb*32+kg*8+j] (zero for k>=784).
#define W1P_DW    12800
#define W2C_ELEMS (16 * 64 * 8)    // bf16, k-chunked
#define W3_ELEMS  (16 * 64)        // bf16

typedef short s16x8 __attribute__((ext_vector_type(8)));
typedef float f32x4 __attribute__((ext_vector_type(4)));
typedef __hip_bfloat16 bf16;

static __device__ __forceinline__ short b2s(float f) {
    bf16 h = __float2bfloat16(f);
    return *reinterpret_cast<short*>(&h);
}
static __device__ __forceinline__ s16x8 cvt8(f32x4 a, f32x4 b) {
    s16x8 r;
    r[0] = b2s(a[0]); r[1] = b2s(a[1]); r[2] = b2s(a[2]); r[3] = b2s(a[3]);
    r[4] = b2s(b[0]); r[5] = b2s(b[1]); r[6] = b2s(b[2]); r[7] = b2s(b[3]);
    return r;
}
// 8 int4 nibbles -> bf16x8 (values -8..7 exact in bf16)
static __device__ __forceinline__ s16x8 unpack8(unsigned d) {
    s16x8 r;
#pragma unroll
    for (int j = 0; j < 8; ++j) {
        int v = ((int)(d << (28 - 4 * j))) >> 28;
        r[j] = b2s((float)v);
    }
    return r;
}
static __device__ __forceinline__ void gl2lds16(const void* g, char* l) {
    __builtin_amdgcn_global_load_lds(
        (const __attribute__((address_space(1))) void*)g,
        (__attribute__((address_space(3))) void*)l, 16, 0, 0);
}
static __device__ __forceinline__ void gl2lds4(const void* g, char* l) {
    __builtin_amdgcn_global_load_lds(
        (const __attribute__((address_space(1))) void*)g,
        (__attribute__((address_space(3))) void*)l, 4, 0, 0);
}

#define WAITV(N) do { asm volatile("s_waitcnt vmcnt(" #N ")" ::: "memory"); \
                      __builtin_amdgcn_sched_barrier(0); } while (0)
#define WAITL()  do { asm volatile("s_waitcnt lgkmcnt(0)" ::: "memory"); \
                      __builtin_amdgcn_sched_barrier(0); } while (0)
#define BAR()    __builtin_amdgcn_s_barrier()

// ---------------- prep: pack W1 int4; dequant W2/W3 to bf16 ------------------
__global__ __launch_bounds__(256) void dequant_kernel(
    const int* __restrict__ w1q, const float* __restrict__ s1,
    const int* __restrict__ w2q, const float* __restrict__ s2,
    const int* __restrict__ w3q, const float* __restrict__ s3,
    unsigned* __restrict__ w1p, bf16* __restrict__ w2c, bf16* __restrict__ w3d)
{
    const int total = W1P_DW + W2C_ELEMS + W3_ELEMS;
    for (int i = blockIdx.x * blockDim.x + threadIdx.x; i < total;
         i += gridDim.x * blockDim.x) {
        if (i < W1P_DW) {
            int kb = i >> 9, rem = i & 511;
            int kg = rem >> 7, col_s = rem & 127;
            int col = (col_s - 8 * kg) & 127;
            unsigned d = 0;
#pragma unroll
            for (int j = 0; j < 8; ++j) {
                int k = kb * 32 + kg * 8 + j;
                unsigned q = 0;
                if (k < KIN) q = (unsigned)w1q[col * KIN + k] & 0xFu;
                d |= q << (4 * j);
            }
            w1p[i] = d;
        } else if (i < W1P_DW + W2C_ELEMS) {
            int t = i - W1P_DW;
            int kb = t >> 9, rem = t & 511;
            int col = rem >> 3, j = rem & 7;
            int k = kb * 8 + j;
            w2c[t] = __float2bfloat16((float)w2q[col * H1N + k] * s2[col]);
        } else {
            int t = i - W1P_DW - W2C_ELEMS;
            int r = t >> 6, c = t & 63;
            float v = 0.0f;
            if (r < OUTN) v = (float)w3q[r * H2N + c] * s3[r];
            w3d[t] = __float2bfloat16(v);
        }
    }
}

// ---------------- fused MLP ------------------------------------------------
// r14 structure with a 3-slot ring and ONE barrier per window:
//   window t: WAITV(4) -> BAR -> ds_reads(slot t%3) -> WAITL ->
//             STAGE(t+2 -> slot (t+2)%3) -> MFMA
// Staging target slot was consumed at window t-1; the top-of-window-t barrier
// (reached only after each wave's t-1 WAITL) proves all cross-wave reads of
// it are done -> the second barrier is unnecessary. LDS 30KB -> 5 blocks/CU.
__global__ __launch_bounds__(256, 5) void mlp_kernel(
    const float* __restrict__ x,
    const unsigned* __restrict__ w1p,
    const bf16*  __restrict__ w2c,
    const bf16*  __restrict__ w3d,
    const float* __restrict__ s1,
    const float* __restrict__ b1,
    const float* __restrict__ b2,
    const float* __restrict__ b3,
    float* __restrict__ out)
{
    __shared__ __align__(16) char lds[30720];
    // A slots: s*8192, s=0..2 (64 rows x 128B, row r at r*128, seg-swizzled)
    // B slots: 24576 + s*2048 (packed int4 window, 512 dwords [kg][col_s])
    // post-loop overlay: h1 [64][132] shorts at 0; h2 [64][68] at 16896.

    const int tid  = threadIdx.x;
    const int lane = tid & 63;
    const int wv   = tid >> 6;
    const int r16  = lane & 15;
    const int kg   = lane >> 4;     // 0..3
    const int kgo  = kg * 8;
    const int rg   = wv >> 1;       // row group 0..1 (32 rows)
    const int cg   = wv & 1;        // col group 0..1 (64 cols)

    const int i3 = lane >> 3;       // staging row-in-group 0..7
    const int i7 = lane & 7;        // staging 16B-slot 0..7
    const int sw = i7 ^ i3;         // swizzled global seg
    const int adj = (sw >= 4) ? 16 : 0;

    const long long rowBlk = (long long)blockIdx.x * 64;
    const float* gA0 = x + (rowBlk + wv * 16 + i3) * (long long)KIN + sw * 4;
    const float* gA1 = gA0 + 8LL * KIN;
    const unsigned* gBp = w1p + wv * 128 + lane;

    const int aoff = (rg * 32 + r16) * 128 + (((2 * kg) ^ (r16 & 7)) * 16);
    const int bcol = cg * 64 + r16 + 8 * kg;

    // stage window w into slot s (uniform 4 vmem ops per wave)
#define STAGE(W, S) do {                                                      \
        char* ad_ = lds + (S) * 8192 + wv * 2048;                             \
        char* bd_ = lds + 24576 + (S) * 2048 + wv * 512;                      \
        if ((W) < 24) {                                                       \
            gl2lds16(gA0 + (W) * 32, ad_);                                    \
            gl2lds16(gA1 + (W) * 32, ad_ + 1024);                             \
            gl2lds4(gBp + (W) * 512, bd_);                                    \
            gl2lds4(gBp + (W) * 512 + 64, bd_ + 256);                         \
        } else {            /* tail: A segs>=4 redirected in-row */           \
            gl2lds16(gA0 + 768 - adj, ad_);                                   \
            gl2lds16(gA1 + 768 - adj, ad_ + 1024);                            \
            gl2lds4(gBp + 24 * 512, bd_);                                     \
            gl2lds4(gBp + 24 * 512 + 64, bd_ + 256);                          \
        }                                                                     \
    } while (0)

    // prologue: windows 0,1 -> slots 0,1 (8 ops airborne)
    STAGE(0, 0);
    STAGE(1, 1);

    f32x4 acc1[2][4];
#pragma unroll
    for (int i = 0; i < 2; ++i)
#pragma unroll
        for (int j = 0; j < 4; ++j) acc1[i][j] = (f32x4){0.f, 0.f, 0.f, 0.f};

    int sc = 0;                     // consume slot = t % 3
    int sn = 2;                     // stage slot = (t+2) % 3
#pragma unroll 1
    for (int t = 0; t < 23; ++t) {
        WAITV(4);                 // window t landed; t+1 stays airborne
        BAR();                    // all waves' window-t shares landed
        const char* sa = lds + sc * 8192;
        f32x4 q00 = *(const f32x4*)(sa + aoff);
        f32x4 q01 = *(const f32x4*)(sa + (aoff ^ 16));
        f32x4 q10 = *(const f32x4*)(sa + aoff + 2048);
        f32x4 q11 = *(const f32x4*)(sa + (aoff ^ 16) + 2048);
        const char* sb = lds + 24576 + sc * 2048 + kg * 512;
        unsigned bw4[4];
#pragma unroll
        for (int nj = 0; nj < 4; ++nj)
            bw4[nj] = *(const unsigned*)(sb + (((bcol + nj * 16) & 127) << 2));
        WAITL();                  // my reads in registers
        STAGE(t + 2, sn);         // slot sn consumed at t-1; top BAR proves free
        s16x8 a0 = cvt8(q00, q01);
        s16x8 a1 = cvt8(q10, q11);
#pragma unroll
        for (int nj = 0; nj < 4; ++nj) {
            s16x8 bf = unpack8(bw4[nj]);
            acc1[0][nj] = __builtin_amdgcn_mfma_f32_16x16x32_bf16(a0, bf, acc1[0][nj], 0, 0, 0);
            acc1[1][nj] = __builtin_amdgcn_mfma_f32_16x16x32_bf16(a1, bf, acc1[1][nj], 0, 0, 0);
        }
        sc = (sc == 2) ? 0 : sc + 1;
        sn = (sn == 2) ? 0 : sn + 1;
    }
    {   // peeled t = 23 (window 24 stays airborne; no stage)
        WAITV(4);
        BAR();
        const char* sa = lds + sc * 8192;
        f32x4 q00 = *(const f32x4*)(sa + aoff);
        f32x4 q01 = *(const f32x4*)(sa + (aoff ^ 16));
        f32x4 q10 = *(const f32x4*)(sa + aoff + 2048);
        f32x4 q11 = *(const f32x4*)(sa + (aoff ^ 16) + 2048);
        const char* sb = lds + 24576 + sc * 2048 + kg * 512;
        unsigned bw4[4];
#pragma unroll
        for (int nj = 0; nj < 4; ++nj)
            bw4[nj] = *(const unsigned*)(sb + (((bcol + nj * 16) & 127) << 2));
        WAITL();
        s16x8 a0 = cvt8(q00, q01);
        s16x8 a1 = cvt8(q10, q11);
#pragma unroll
        for (int nj = 0; nj < 4; ++nj) {
            s16x8 bf = unpack8(bw4[nj]);
            acc1[0][nj] = __builtin_amdgcn_mfma_f32_16x16x32_bf16(a0, bf, acc1[0][nj], 0, 0, 0);
            acc1[1][nj] = __builtin_amdgcn_mfma_f32_16x16x32_bf16(a1, bf, acc1[1][nj], 0, 0, 0);
        }
        sc = (sc == 2) ? 0 : sc + 1;
    }
    {   // peeled t = 24 (window 24, k 768..799; packed weights zero k>=784)
        WAITV(0);
        BAR();
        const char* sa = lds + sc * 8192;
        f32x4 q00 = *(const f32x4*)(sa + aoff);
        f32x4 q01 = *(const f32x4*)(sa + (aoff ^ 16));
        f32x4 q10 = *(const f32x4*)(sa + aoff + 2048);
        f32x4 q11 = *(const f32x4*)(sa + (aoff ^ 16) + 2048);
        const char* sb = lds + 24576 + sc * 2048 + kg * 512;
        unsigned bw4[4];
#pragma unroll
        for (int nj = 0; nj < 4; ++nj)
            bw4[nj] = *(const unsigned*)(sb + (((bcol + nj * 16) & 127) << 2));
        WAITL();
        BAR();                    // all waves done reading -> arenas may overlay
        s16x8 a0 = cvt8(q00, q01);
        s16x8 a1 = cvt8(q10, q11);
#pragma unroll
        for (int nj = 0; nj < 4; ++nj) {
            s16x8 bf = unpack8(bw4[nj]);
            acc1[0][nj] = __builtin_amdgcn_mfma_f32_16x16x32_bf16(a0, bf, acc1[0][nj], 0, 0, 0);
            acc1[1][nj] = __builtin_amdgcn_mfma_f32_16x16x32_bf16(a1, bf, acc1[1][nj], 0, 0, 0);
        }
    }
#undef STAGE

    // ---- h1 (block-level [64][132] shorts at lds+0): scale+bias+relu -------
    short* h1s = (short*)lds;
#pragma unroll
    for (int nj = 0; nj < 4; ++nj) {
        const int col = cg * 64 + nj * 16 + r16;
        const float sc1 = s1[col];
        const float bb = b1[col];
#pragma unroll
        for (int mi = 0; mi < 2; ++mi)
#pragma unroll
            for (int r = 0; r < 4; ++r) {
                const int row = rg * 32 + mi * 16 + kg * 4 + r;
                h1s[row * 132 + col] = b2s(fmaxf(acc1[mi][nj][r] * sc1 + bb, 0.0f));
            }
    }
    __syncthreads();   // h1 rows cross wave boundaries

    // ---- layer 2: [16 x 128] @ [128 x 64] per wave (rows wv*16..) ----------
    f32x4 acc2[4];
#pragma unroll
    for (int j = 0; j < 4; ++j) acc2[j] = (f32x4){0.f, 0.f, 0.f, 0.f};

#pragma unroll
    for (int it = 0; it < 4; ++it) {
        const int kk = it * 32 + kgo;
        s16x8 a = *(const s16x8*)(h1s + (wv * 16 + r16) * 132 + kk);
        const bf16* bp2 = w2c + (size_t)(it * 4 + kg) * 512 + (size_t)r16 * 8;
#pragma unroll
        for (int nj = 0; nj < 4; ++nj) {
            s16x8 b = *(const s16x8*)(bp2 + nj * 128);
            acc2[nj] = __builtin_amdgcn_mfma_f32_16x16x32_bf16(a, b, acc2[nj], 0, 0, 0);
        }
    }

    // h2 at lds+16896: [64][68] shorts; wave writes/reads its own 16 rows
    short* h2s = (short*)(lds + 16896);
#pragma unroll
    for (int nj = 0; nj < 4; ++nj) {
        const int col = nj * 16 + r16;
        const float bb = b2[col];
#pragma unroll
        for (int r = 0; r < 4; ++r)
            h2s[(wv * 16 + kg * 4 + r) * 68 + col] = b2s(fmaxf(acc2[nj][r] + bb, 0.0f));
    }

    // ---- layer 3: [16 x 64] @ [64 x 16] (rows 10..15 of W3 zero) -----------
    f32x4 acc3 = (f32x4){0.f, 0.f, 0.f, 0.f};
#pragma unroll
    for (int it = 0; it < 2; ++it) {
        const int kk = it * 32 + kgo;
        s16x8 a = *(const s16x8*)(h2s + (wv * 16 + r16) * 68 + kk);
        s16x8 b = *(const s16x8*)(w3d + r16 * H2N + kk);
        acc3 = __builtin_amdgcn_mfma_f32_16x16x32_bf16(a, b, acc3, 0, 0, 0);
    }

    // out stage in wave's own (dead) h1 rows
    float* ob = (float*)(lds + (wv * 16) * 264);
    const float bb3 = (r16 < OUTN) ? b3[r16] : 0.0f;
#pragma unroll
    for (int r = 0; r < 4; ++r) {
        const int row = kg * 4 + r;
        if (r16 < OUTN) ob[row * OUTN + r16] = acc3[r] + bb3;
    }
    const long long obase = (rowBlk + wv * 16) * OUTN;
    for (int i = lane; i < 16 * OUTN; i += 64) out[obase + i] = ob[i];
}

extern "C" void kernel_launch(void* const* d_in, const int* in_sizes, int n_in,
                              void* d_out, int out_size, void* d_ws, size_t ws_size,
                              hipStream_t stream) {
    const float* x   = (const float*)d_in[0];
    const int*   w1q = (const int*)d_in[1];
    const float* s1  = (const float*)d_in[2];
    const float* b1  = (const float*)d_in[3];
    const int*   w2q = (const int*)d_in[4];
    const float* s2  = (const float*)d_in[5];
    const float* b2  = (const float*)d_in[6];
    const int*   w3q = (const int*)d_in[7];
    const float* s3  = (const float*)d_in[8];
    const float* b3  = (const float*)d_in[9];
    float* out = (float*)d_out;

    unsigned* w1p = (unsigned*)d_ws;           // 12800 dwords
    bf16* w2c = (bf16*)(w1p + W1P_DW);         // [16][64][8]
    bf16* w3d = w2c + W2C_ELEMS;               // [16][64]

    dequant_kernel<<<128, 256, 0, stream>>>(w1q, s1, w2q, s2, w3q, s3, w1p, w2c, w3d);
    mlp_kernel<<<NROWS / 64, 256, 0, stream>>>(x, w1p, w2c, w3d, s1, b1, b2, b3, out);
}